// Round 7
// baseline (131.128 us; speedup 1.0000x reference)
//
#include <hip/hip_runtime.h>

#define NODES 50000
#define NEDGES 800000
#define NIN 512
#define NHID 64
#define CAP 64   // per-row bucket capacity; P(Poisson(16) > 64) ~ 2e-18

typedef __attribute__((ext_vector_type(8))) short short8v;           // 8 bf16
typedef __attribute__((ext_vector_type(8))) unsigned short ushort8v; // 8 bf16
typedef __attribute__((ext_vector_type(4))) float f32x4;

// ws layout in 4-byte words
#define H_OFF    0           // 1,600,000 words: h bf16 (3.2M elems)
#define WBF_OFF  1600000     // 16,384 words: W bf16
#define CNT_OFF  1616384     // 50,000 words: per-row counts (atomic cursors)
#define ECV_OFF  1666384     // 6,400,000 words: 50K rows x 64 slots x int2(col,val)
// end = 8,066,384 words = 32.3 MB

__device__ inline unsigned short f2bf(float f) {
  unsigned u = __builtin_bit_cast(unsigned, f);
  u += 0x7FFF + ((u >> 16) & 1);          // RNE
  return (unsigned short)(u >> 16);
}
__device__ inline float bf2f(unsigned short u) {
  return __builtin_bit_cast(float, (unsigned)u << 16);
}

// ---------- fused init: zero cnt + W fp32->bf16 ----------
__global__ __launch_bounds__(256) void init_kernel(
    const float* __restrict__ W, unsigned int* __restrict__ wbf,
    int* __restrict__ cnt)
{
  int i = blockIdx.x * 256 + threadIdx.x;
  if (i < NIN * NHID / 2) {
    float2 w = reinterpret_cast<const float2*>(W)[i];
    wbf[i] = (unsigned)f2bf(w.x) | ((unsigned)f2bf(w.y) << 16);
  }
  if (i < NODES) cnt[i] = 0;
}

// ---------- direct binning: one atomic per edge does hist+placement ----------
__global__ __launch_bounds__(256) void bucket_kernel(
    const int* __restrict__ rows, const int* __restrict__ cols,
    const float* __restrict__ vals, int* __restrict__ cnt,
    int2* __restrict__ ecv)
{
  int e = blockIdx.x * 256 + threadIdx.x;
  if (e < NEDGES) {
    int r = rows[e];
    int slot = atomicAdd(&cnt[r], 1);
    if (slot < CAP)
      ecv[(long)r * CAP + slot] = make_int2(cols[e], __float_as_int(vals[e]));
  }
}

// ---------- MFMA GEMM: h[n][f] = bf16( sum_k x[n][k]*W[f][k] + b[f] ) ----------
// one wave (= one 64-thread block) per 16 nodes; entire K=512 strip preloaded
__global__ __launch_bounds__(64) void gemm_kernel(
    const float* __restrict__ x, const unsigned short* __restrict__ wbf,
    const float* __restrict__ b, unsigned short* __restrict__ h)
{
  int gw = blockIdx.x;                // 3125 waves exactly
  int lane = (int)(threadIdx.x & 63);
  int r16 = lane & 15;                // A-row / D-col select
  int kg  = lane >> 4;                // k-group 0..3

  const float4* xp = reinterpret_cast<const float4*>(
      x + (long)(gw * 16 + r16) * NIN + kg * 8);
  const unsigned short* wp = wbf + (long)r16 * NIN + kg * 8;

  float4 xb[32];
  #pragma unroll
  for (int s = 0; s < 16; ++s) {
    xb[2 * s]     = xp[8 * s];
    xb[2 * s + 1] = xp[8 * s + 1];
  }

  f32x4 acc[4] = {{0,0,0,0},{0,0,0,0},{0,0,0,0},{0,0,0,0}};

  #pragma unroll
  for (int s = 0; s < 16; ++s) {
    float4 a0 = xb[2 * s];
    float4 a1 = xb[2 * s + 1];
    short8v af;
    af[0] = (short)f2bf(a0.x); af[1] = (short)f2bf(a0.y);
    af[2] = (short)f2bf(a0.z); af[3] = (short)f2bf(a0.w);
    af[4] = (short)f2bf(a1.x); af[5] = (short)f2bf(a1.y);
    af[6] = (short)f2bf(a1.z); af[7] = (short)f2bf(a1.w);
    #pragma unroll
    for (int ft = 0; ft < 4; ++ft) {
      short8v bfr = *reinterpret_cast<const short8v*>(
          wp + (long)ft * 16 * NIN + s * 32);
      acc[ft] = __builtin_amdgcn_mfma_f32_16x16x32_bf16(af, bfr, acc[ft], 0, 0, 0);
    }
  }

  int n0 = gw * 16 + kg * 4;
  #pragma unroll
  for (int ft = 0; ft < 4; ++ft) {
    float bias = b[ft * 16 + r16];
    #pragma unroll
    for (int r = 0; r < 4; ++r)
      h[(long)(n0 + r) * NHID + ft * 16 + r16] = f2bf(acc[ft][r] + bias);
  }
}

// ---------- gather, split by feature half so the h slice is L2-resident ----------
// wave per (row, half): 16 edge groups x 4 lanes; lane covers 8 features.
// half 0 -> features 0..31 (h slice 3.2MB), half 1 -> features 32..63.
__global__ __launch_bounds__(256) void gather_kernel(
    const int* __restrict__ cnt, const int2* __restrict__ ecv,
    const unsigned short* __restrict__ h, const float* __restrict__ alpha,
    float* __restrict__ out)
{
  int gw = (int)((blockIdx.x * 256 + threadIdx.x) >> 6);   // 0..2*NODES-1
  int half = (gw >= NODES) ? 1 : 0;     // block order: all half-0 first
  int wid = gw - half * NODES;
  int lane = (int)(threadIdx.x & 63);
  int eg = lane >> 2;                   // edge group 0..15
  int f0 = half * 32 + (lane & 3) * 8;  // 8 features per lane

  int deg = cnt[wid];
  if (deg > CAP) deg = CAP;
  const int2* base = ecv + (long)wid * CAP;
  float a = alpha[0];

  float acc[8] = {0.f, 0.f, 0.f, 0.f, 0.f, 0.f, 0.f, 0.f};
  int j = eg;
  int2 e = (j < deg) ? base[j] : make_int2(0, 0);
  while (j < deg) {
    int2 en = (j + 16 < deg) ? base[j + 16] : make_int2(0, 0);   // prefetch
    float v = __int_as_float(e.y);
    ushort8v hv = *reinterpret_cast<const ushort8v*>(&h[(long)e.x * NHID + f0]);
    #pragma unroll
    for (int k = 0; k < 8; ++k)
      acc[k] = fmaf(v, bf2f(hv[k]), acc[k]);
    e = en;
    j += 16;
  }

  #pragma unroll
  for (int k = 0; k < 8; ++k) {
    acc[k] += __shfl_xor(acc[k], 4);
    acc[k] += __shfl_xor(acc[k], 8);
    acc[k] += __shfl_xor(acc[k], 16);
    acc[k] += __shfl_xor(acc[k], 32);
  }

  if (eg == 0) {
    float4 o0, o1;
    o0.x = acc[0] >= 0.f ? acc[0] : a * acc[0];
    o0.y = acc[1] >= 0.f ? acc[1] : a * acc[1];
    o0.z = acc[2] >= 0.f ? acc[2] : a * acc[2];
    o0.w = acc[3] >= 0.f ? acc[3] : a * acc[3];
    o1.x = acc[4] >= 0.f ? acc[4] : a * acc[4];
    o1.y = acc[5] >= 0.f ? acc[5] : a * acc[5];
    o1.z = acc[6] >= 0.f ? acc[6] : a * acc[6];
    o1.w = acc[7] >= 0.f ? acc[7] : a * acc[7];
    *reinterpret_cast<float4*>(&out[(long)wid * NHID + f0]) = o0;
    *reinterpret_cast<float4*>(&out[(long)wid * NHID + f0 + 4]) = o1;
  }
}

extern "C" void kernel_launch(void* const* d_in, const int* in_sizes, int n_in,
                              void* d_out, int out_size, void* d_ws, size_t ws_size,
                              hipStream_t stream) {
  const float* x     = (const float*)d_in[0];
  const int*   rows  = (const int*)d_in[1];
  const int*   cols  = (const int*)d_in[2];
  const float* vals  = (const float*)d_in[3];
  const float* W     = (const float*)d_in[4];
  const float* b     = (const float*)d_in[5];
  const float* alpha = (const float*)d_in[6];
  float* out = (float*)d_out;

  float* wsf = (float*)d_ws;
  unsigned short* h   = (unsigned short*)(wsf + H_OFF);
  unsigned int*   wbf = (unsigned int*)(wsf + WBF_OFF);
  int*            cnt = (int*)(wsf + CNT_OFF);
  int2*           ecv = (int2*)(wsf + ECV_OFF);

  init_kernel<<<(NODES + 255) / 256, 256, 0, stream>>>(W, wbf, cnt);
  bucket_kernel<<<(NEDGES + 255) / 256, 256, 0, stream>>>(rows, cols, vals, cnt, ecv);
  gemm_kernel<<<NODES / 16, 64, 0, stream>>>(
      x, (const unsigned short*)wbf, b, h);
  gather_kernel<<<2 * NODES * 64 / 256, 256, 0, stream>>>(cnt, ecv, h, alpha, out);
}

// Round 8
// 103.946 us; speedup vs baseline: 1.2615x; 1.2615x over previous
//
#include <hip/hip_runtime.h>

#define NODES 50000
#define NEDGES 800000
#define NIN 512
#define NHID 64
#define CAP 64   // per-row bucket capacity; P(Poisson(16) > 64) ~ 2e-18

typedef __attribute__((ext_vector_type(8))) short short8v;           // 8 bf16
typedef __attribute__((ext_vector_type(8))) unsigned short ushort8v; // 8 bf16
typedef __attribute__((ext_vector_type(4))) float f32x4;

// ws layout in 4-byte words
#define H_OFF    0           // 1,600,000 words: h bf16 (3.2M elems)
#define WBF_OFF  1600000     // 16,384 words: W bf16
#define CNT_OFF  1616384     // 50,000 words: per-row counts (atomic cursors)
#define ECV_OFF  1666384     // 6,400,000 words: 50K rows x 64 slots x int2(col,val)
// end = 8,066,384 words = 32.3 MB

__device__ inline unsigned short f2bf(float f) {
  unsigned u = __builtin_bit_cast(unsigned, f);
  u += 0x7FFF + ((u >> 16) & 1);          // RNE
  return (unsigned short)(u >> 16);
}
__device__ inline float bf2f(unsigned short u) {
  return __builtin_bit_cast(float, (unsigned)u << 16);
}

// ---------- fused init: zero cnt + W fp32->bf16 ----------
__global__ __launch_bounds__(256) void init_kernel(
    const float* __restrict__ W, unsigned int* __restrict__ wbf,
    int* __restrict__ cnt)
{
  int i = blockIdx.x * 256 + threadIdx.x;
  if (i < NIN * NHID / 2) {
    float2 w = reinterpret_cast<const float2*>(W)[i];
    wbf[i] = (unsigned)f2bf(w.x) | ((unsigned)f2bf(w.y) << 16);
  }
  if (i < NODES) cnt[i] = 0;
}

// ---------- fat kernel: even blocks = MFMA gemm, odd blocks = edge binning ----
// gemm: one wave per 16 nodes, whole K=512 strip preloaded (32 loads in flight).
// bucket: 4 edges per thread, vectorized loads, 4 independent atomic chains.
// The two parts are data-independent; interleaving overlaps gemm's VALU/MFMA
// with bucket's scatter-write latency.
__global__ __launch_bounds__(64) void fat_kernel(
    const float* __restrict__ x, const unsigned short* __restrict__ wbf,
    const float* __restrict__ b, unsigned short* __restrict__ h,
    const int* __restrict__ rows, const int* __restrict__ cols,
    const float* __restrict__ vals, int* __restrict__ cnt,
    int2* __restrict__ ecv)
{
  int bid = blockIdx.x;

  if (bid & 1) {
    // ---------------- bucket part: odd blocks, 3125 x 64 thr x 4 edges ------
    int t = (bid >> 1) * 64 + (int)threadIdx.x;   // 0..199999
    int e0 = t * 4;                               // exact: 200000*4 = NEDGES
    int4   r4 = *reinterpret_cast<const int4*>(rows + e0);
    int4   c4 = *reinterpret_cast<const int4*>(cols + e0);
    float4 v4 = *reinterpret_cast<const float4*>(vals + e0);
    int s0 = atomicAdd(&cnt[r4.x], 1);
    int s1 = atomicAdd(&cnt[r4.y], 1);
    int s2 = atomicAdd(&cnt[r4.z], 1);
    int s3 = atomicAdd(&cnt[r4.w], 1);
    if (s0 < CAP) ecv[(long)r4.x * CAP + s0] = make_int2(c4.x, __float_as_int(v4.x));
    if (s1 < CAP) ecv[(long)r4.y * CAP + s1] = make_int2(c4.y, __float_as_int(v4.y));
    if (s2 < CAP) ecv[(long)r4.z * CAP + s2] = make_int2(c4.z, __float_as_int(v4.z));
    if (s3 < CAP) ecv[(long)r4.w * CAP + s3] = make_int2(c4.w, __float_as_int(v4.w));
    return;
  }

  // ---------------- gemm part: even blocks, gw = 0..3124 --------------------
  int gw = bid >> 1;
  int lane = (int)(threadIdx.x & 63);
  int r16 = lane & 15;                // A-row / D-col select
  int kg  = lane >> 4;                // k-group 0..3

  const float4* xp = reinterpret_cast<const float4*>(
      x + (long)(gw * 16 + r16) * NIN + kg * 8);
  const unsigned short* wp = wbf + (long)r16 * NIN + kg * 8;

  float4 xb[32];
  #pragma unroll
  for (int s = 0; s < 16; ++s) {
    xb[2 * s]     = xp[8 * s];
    xb[2 * s + 1] = xp[8 * s + 1];
  }

  f32x4 acc[4] = {{0,0,0,0},{0,0,0,0},{0,0,0,0},{0,0,0,0}};

  #pragma unroll
  for (int s = 0; s < 16; ++s) {
    float4 a0 = xb[2 * s];
    float4 a1 = xb[2 * s + 1];
    short8v af;
    af[0] = (short)f2bf(a0.x); af[1] = (short)f2bf(a0.y);
    af[2] = (short)f2bf(a0.z); af[3] = (short)f2bf(a0.w);
    af[4] = (short)f2bf(a1.x); af[5] = (short)f2bf(a1.y);
    af[6] = (short)f2bf(a1.z); af[7] = (short)f2bf(a1.w);
    #pragma unroll
    for (int ft = 0; ft < 4; ++ft) {
      short8v bfr = *reinterpret_cast<const short8v*>(
          wp + (long)ft * 16 * NIN + s * 32);
      acc[ft] = __builtin_amdgcn_mfma_f32_16x16x32_bf16(af, bfr, acc[ft], 0, 0, 0);
    }
  }

  // D: col(f) = lane&15, row(node) = kg*4 + reg
  int n0 = gw * 16 + kg * 4;
  #pragma unroll
  for (int ft = 0; ft < 4; ++ft) {
    float bias = b[ft * 16 + r16];
    #pragma unroll
    for (int r = 0; r < 4; ++r)
      h[(long)(n0 + r) * NHID + ft * 16 + r16] = f2bf(acc[ft][r] + bias);
  }
}

// ---------- gather: wave per row, 8 edges in flight, pipelined, +LeakyReLU ----------
__global__ __launch_bounds__(256) void gather_kernel(
    const int* __restrict__ cnt, const int2* __restrict__ ecv,
    const unsigned short* __restrict__ h, const float* __restrict__ alpha,
    float* __restrict__ out)
{
  int wid = (int)((blockIdx.x * 256 + threadIdx.x) >> 6);
  if (wid >= NODES) return;
  int lane = (int)(threadIdx.x & 63);
  int eg = lane >> 3;          // edge group 0..7
  int fo = lane & 7;           // feature octet 0..7 -> features fo*8..fo*8+7
  int deg = cnt[wid];
  if (deg > CAP) deg = CAP;
  const int2* base = ecv + (long)wid * CAP;
  float a = alpha[0];

  float acc[8] = {0.f, 0.f, 0.f, 0.f, 0.f, 0.f, 0.f, 0.f};
  int j = eg;
  int2 e = (j < deg) ? base[j] : make_int2(0, 0);
  while (j < deg) {
    int2 en = (j + 8 < deg) ? base[j + 8] : make_int2(0, 0);   // prefetch
    float v = __int_as_float(e.y);
    ushort8v hv = *reinterpret_cast<const ushort8v*>(&h[(long)e.x * NHID + fo * 8]);
    #pragma unroll
    for (int k = 0; k < 8; ++k)
      acc[k] = fmaf(v, bf2f(hv[k]), acc[k]);
    e = en;
    j += 8;
  }

  #pragma unroll
  for (int k = 0; k < 8; ++k) {
    acc[k] += __shfl_xor(acc[k], 8);
    acc[k] += __shfl_xor(acc[k], 16);
    acc[k] += __shfl_xor(acc[k], 32);
  }

  if (eg == 0) {
    float4 o0, o1;
    o0.x = acc[0] >= 0.f ? acc[0] : a * acc[0];
    o0.y = acc[1] >= 0.f ? acc[1] : a * acc[1];
    o0.z = acc[2] >= 0.f ? acc[2] : a * acc[2];
    o0.w = acc[3] >= 0.f ? acc[3] : a * acc[3];
    o1.x = acc[4] >= 0.f ? acc[4] : a * acc[4];
    o1.y = acc[5] >= 0.f ? acc[5] : a * acc[5];
    o1.z = acc[6] >= 0.f ? acc[6] : a * acc[6];
    o1.w = acc[7] >= 0.f ? acc[7] : a * acc[7];
    *reinterpret_cast<float4*>(&out[(long)wid * NHID + fo * 8]) = o0;
    *reinterpret_cast<float4*>(&out[(long)wid * NHID + fo * 8 + 4]) = o1;
  }
}

extern "C" void kernel_launch(void* const* d_in, const int* in_sizes, int n_in,
                              void* d_out, int out_size, void* d_ws, size_t ws_size,
                              hipStream_t stream) {
  const float* x     = (const float*)d_in[0];
  const int*   rows  = (const int*)d_in[1];
  const int*   cols  = (const int*)d_in[2];
  const float* vals  = (const float*)d_in[3];
  const float* W     = (const float*)d_in[4];
  const float* b     = (const float*)d_in[5];
  const float* alpha = (const float*)d_in[6];
  float* out = (float*)d_out;

  float* wsf = (float*)d_ws;
  unsigned short* h   = (unsigned short*)(wsf + H_OFF);
  unsigned int*   wbf = (unsigned int*)(wsf + WBF_OFF);
  int*            cnt = (int*)(wsf + CNT_OFF);
  int2*           ecv = (int2*)(wsf + ECV_OFF);

  init_kernel<<<(NODES + 255) / 256, 256, 0, stream>>>(W, wbf, cnt);
  // even blocks: 3125 gemm waves; odd blocks: 3125 bucket blocks (4 edges/thr)
  fat_kernel<<<6250, 64, 0, stream>>>(
      x, (const unsigned short*)wbf, b, h, rows, cols, vals, cnt, ecv);
  gather_kernel<<<NODES * 64 / 256, 256, 0, stream>>>(cnt, ecv, h, alpha, out);
}

// Round 9
// 89.601 us; speedup vs baseline: 1.4635x; 1.1601x over previous
//
#include <hip/hip_runtime.h>

#define NODES 50000
#define NEDGES 800000
#define NIN 512
#define NHID 64
#define CAP 64        // per-row bucket capacity; P(Poisson(16) > 64) ~ 2e-18
#define NQUAD 200000  // NEDGES / 4
#define BB 2048       // bucket blocks: 8 row-groups x 256 sub-blocks
#define ROWS_PER_G (NODES / 8)   // 6250

typedef __attribute__((ext_vector_type(8))) short short8v;           // 8 bf16
typedef __attribute__((ext_vector_type(8))) unsigned short ushort8v; // 8 bf16
typedef __attribute__((ext_vector_type(4))) float f32x4;

// ws layout in 4-byte words
#define H_OFF    0           // 1,600,000 words: h bf16 (3.2M elems)
#define WBF_OFF  1600000     // 16,384 words: W bf16
#define CNT_OFF  1616384     // 50,000 words: per-row counts (atomic cursors)
#define ECV_OFF  1666384     // 6,400,000 words: 50K rows x 64 slots x int2(col,val)
// end = 8,066,384 words = 32.3 MB

__device__ inline unsigned short f2bf(float f) {
  unsigned u = __builtin_bit_cast(unsigned, f);
  u += 0x7FFF + ((u >> 16) & 1);          // RNE
  return (unsigned short)(u >> 16);
}
__device__ inline float bf2f(unsigned short u) {
  return __builtin_bit_cast(float, (unsigned)u << 16);
}

// ---------- fused init: zero cnt + W fp32->bf16 ----------
__global__ __launch_bounds__(256) void init_kernel(
    const float* __restrict__ W, unsigned int* __restrict__ wbf,
    int* __restrict__ cnt)
{
  int i = blockIdx.x * 256 + threadIdx.x;
  if (i < NIN * NHID / 2) {
    float2 w = reinterpret_cast<const float2*>(W)[i];
    wbf[i] = (unsigned)f2bf(w.x) | ((unsigned)f2bf(w.y) << 16);
  }
  if (i < NODES) cnt[i] = 0;
}

// ---------- fat kernel ------------------------------------------------------
// blocks [0, BB): XCD-partitioned edge binning.
//   group g = blockIdx & 7 owns rows [g*6250, (g+1)*6250) -> its ecv slice is
//   3.2 MB, L2-resident on one XCD (round-robin dispatch puts all blocks with
//   equal blockIdx&7 on the same XCD). Each group streams ALL edges (8x
//   re-read, coalesced, L3-hot) and bins only its own rows -> scattered 8B
//   stores coalesce in the local L2 instead of thrashing 8 L2s.
// blocks [BB, BB+3125): MFMA gemm, one wave per 16 nodes, K strip preloaded.
__global__ __launch_bounds__(64) void fat_kernel(
    const float* __restrict__ x, const unsigned short* __restrict__ wbf,
    const float* __restrict__ b, unsigned short* __restrict__ h,
    const int* __restrict__ rows, const int* __restrict__ cols,
    const float* __restrict__ vals, int* __restrict__ cnt,
    int2* __restrict__ ecv)
{
  int bid = blockIdx.x;

  if (bid < BB) {
    // ---------------- binning part ------------------------------------------
    int g = bid & 7;                       // row group == target XCD
    int sub = bid >> 3;                    // 0..255 within group
    int r_lo = g * ROWS_PER_G;
    int r_hi = r_lo + ROWS_PER_G;

    for (int q = sub * 64 + (int)threadIdx.x; q < NQUAD; q += (BB / 8) * 64) {
      int e0 = q * 4;
      int4   r4 = *reinterpret_cast<const int4*>(rows + e0);
      int4   c4 = *reinterpret_cast<const int4*>(cols + e0);
      float4 v4 = *reinterpret_cast<const float4*>(vals + e0);
      if (r4.x >= r_lo && r4.x < r_hi) {
        int s = atomicAdd(&cnt[r4.x], 1);
        if (s < CAP) ecv[(long)r4.x * CAP + s] = make_int2(c4.x, __float_as_int(v4.x));
      }
      if (r4.y >= r_lo && r4.y < r_hi) {
        int s = atomicAdd(&cnt[r4.y], 1);
        if (s < CAP) ecv[(long)r4.y * CAP + s] = make_int2(c4.y, __float_as_int(v4.y));
      }
      if (r4.z >= r_lo && r4.z < r_hi) {
        int s = atomicAdd(&cnt[r4.z], 1);
        if (s < CAP) ecv[(long)r4.z * CAP + s] = make_int2(c4.z, __float_as_int(v4.z));
      }
      if (r4.w >= r_lo && r4.w < r_hi) {
        int s = atomicAdd(&cnt[r4.w], 1);
        if (s < CAP) ecv[(long)r4.w * CAP + s] = make_int2(c4.w, __float_as_int(v4.w));
      }
    }
    return;
  }

  // ---------------- gemm part: gw = 0..3124 ---------------------------------
  int gw = bid - BB;
  int lane = (int)(threadIdx.x & 63);
  int r16 = lane & 15;                // A-row / D-col select
  int kg  = lane >> 4;                // k-group 0..3

  const float4* xp = reinterpret_cast<const float4*>(
      x + (long)(gw * 16 + r16) * NIN + kg * 8);
  const unsigned short* wp = wbf + (long)r16 * NIN + kg * 8;

  float4 xb[32];
  #pragma unroll
  for (int s = 0; s < 16; ++s) {
    xb[2 * s]     = xp[8 * s];
    xb[2 * s + 1] = xp[8 * s + 1];
  }

  f32x4 acc[4] = {{0,0,0,0},{0,0,0,0},{0,0,0,0},{0,0,0,0}};

  #pragma unroll
  for (int s = 0; s < 16; ++s) {
    float4 a0 = xb[2 * s];
    float4 a1 = xb[2 * s + 1];
    short8v af;
    af[0] = (short)f2bf(a0.x); af[1] = (short)f2bf(a0.y);
    af[2] = (short)f2bf(a0.z); af[3] = (short)f2bf(a0.w);
    af[4] = (short)f2bf(a1.x); af[5] = (short)f2bf(a1.y);
    af[6] = (short)f2bf(a1.z); af[7] = (short)f2bf(a1.w);
    #pragma unroll
    for (int ft = 0; ft < 4; ++ft) {
      short8v bfr = *reinterpret_cast<const short8v*>(
          wp + (long)ft * 16 * NIN + s * 32);
      acc[ft] = __builtin_amdgcn_mfma_f32_16x16x32_bf16(af, bfr, acc[ft], 0, 0, 0);
    }
  }

  // D: col(f) = lane&15, row(node) = kg*4 + reg
  int n0 = gw * 16 + kg * 4;
  #pragma unroll
  for (int ft = 0; ft < 4; ++ft) {
    float bias = b[ft * 16 + r16];
    #pragma unroll
    for (int r = 0; r < 4; ++r)
      h[(long)(n0 + r) * NHID + ft * 16 + r16] = f2bf(acc[ft][r] + bias);
  }
}

// ---------- gather: wave per row, 8 edges in flight, pipelined, +LeakyReLU ----------
__global__ __launch_bounds__(256) void gather_kernel(
    const int* __restrict__ cnt, const int2* __restrict__ ecv,
    const unsigned short* __restrict__ h, const float* __restrict__ alpha,
    float* __restrict__ out)
{
  int wid = (int)((blockIdx.x * 256 + threadIdx.x) >> 6);
  if (wid >= NODES) return;
  int lane = (int)(threadIdx.x & 63);
  int eg = lane >> 3;          // edge group 0..7
  int fo = lane & 7;           // feature octet 0..7 -> features fo*8..fo*8+7
  int deg = cnt[wid];
  if (deg > CAP) deg = CAP;
  const int2* base = ecv + (long)wid * CAP;
  float a = alpha[0];

  float acc[8] = {0.f, 0.f, 0.f, 0.f, 0.f, 0.f, 0.f, 0.f};
  int j = eg;
  int2 e = (j < deg) ? base[j] : make_int2(0, 0);
  while (j < deg) {
    int2 en = (j + 8 < deg) ? base[j + 8] : make_int2(0, 0);   // prefetch
    float v = __int_as_float(e.y);
    ushort8v hv = *reinterpret_cast<const ushort8v*>(&h[(long)e.x * NHID + fo * 8]);
    #pragma unroll
    for (int k = 0; k < 8; ++k)
      acc[k] = fmaf(v, bf2f(hv[k]), acc[k]);
    e = en;
    j += 8;
  }

  #pragma unroll
  for (int k = 0; k < 8; ++k) {
    acc[k] += __shfl_xor(acc[k], 8);
    acc[k] += __shfl_xor(acc[k], 16);
    acc[k] += __shfl_xor(acc[k], 32);
  }

  if (eg == 0) {
    float4 o0, o1;
    o0.x = acc[0] >= 0.f ? acc[0] : a * acc[0];
    o0.y = acc[1] >= 0.f ? acc[1] : a * acc[1];
    o0.z = acc[2] >= 0.f ? acc[2] : a * acc[2];
    o0.w = acc[3] >= 0.f ? acc[3] : a * acc[3];
    o1.x = acc[4] >= 0.f ? acc[4] : a * acc[4];
    o1.y = acc[5] >= 0.f ? acc[5] : a * acc[5];
    o1.z = acc[6] >= 0.f ? acc[6] : a * acc[6];
    o1.w = acc[7] >= 0.f ? acc[7] : a * acc[7];
    *reinterpret_cast<float4*>(&out[(long)wid * NHID + fo * 8]) = o0;
    *reinterpret_cast<float4*>(&out[(long)wid * NHID + fo * 8 + 4]) = o1;
  }
}

extern "C" void kernel_launch(void* const* d_in, const int* in_sizes, int n_in,
                              void* d_out, int out_size, void* d_ws, size_t ws_size,
                              hipStream_t stream) {
  const float* x     = (const float*)d_in[0];
  const int*   rows  = (const int*)d_in[1];
  const int*   cols  = (const int*)d_in[2];
  const float* vals  = (const float*)d_in[3];
  const float* W     = (const float*)d_in[4];
  const float* b     = (const float*)d_in[5];
  const float* alpha = (const float*)d_in[6];
  float* out = (float*)d_out;

  float* wsf = (float*)d_ws;
  unsigned short* h   = (unsigned short*)(wsf + H_OFF);
  unsigned int*   wbf = (unsigned int*)(wsf + WBF_OFF);
  int*            cnt = (int*)(wsf + CNT_OFF);
  int2*           ecv = (int2*)(wsf + ECV_OFF);

  init_kernel<<<(NODES + 255) / 256, 256, 0, stream>>>(W, wbf, cnt);
  // blocks [0,2048): XCD-partitioned binning; [2048, 2048+3125): gemm
  fat_kernel<<<BB + NODES / 16, 64, 0, stream>>>(
      x, (const unsigned short*)wbf, b, h, rows, cols, vals, cnt, ecv);
  gather_kernel<<<NODES * 64 / 256, 256, 0, stream>>>(cnt, ecv, h, alpha, out);
}